// Round 1
// baseline (4449.022 us; speedup 1.0000x reference)
//
#include <hip/hip_runtime.h>

// Problem: VectorQuantizer — z:(16,256,64,64) f32, emb:(1024,256) f32 (row-normalized)
// flat_z rows are CONTIGUOUS 256-float chunks of z (torch .view semantics).
// N=65536 rows, D=256, K=1024.
// d_out layout (float32): q[16777216] | vq_loss[1] | indices_as_float[65536]

#define N_ROWS   65536
#define DIM      256
#define NCODE    1024
#define TILE_M   64          // rows per block
#define KCHUNK   128         // codes per k-chunk
#define DSLICE   32          // d per staged e-slice

// ---------------- kernel 0: embedding row norms ----------------
__global__ __launch_bounds__(256)
void enorm_kernel(const float* __restrict__ emb, float* __restrict__ enorm) {
    const int wv = threadIdx.x >> 6, ln = threadIdx.x & 63;
    const int k = blockIdx.x * 4 + wv;
    const float4 v = *reinterpret_cast<const float4*>(emb + (size_t)k * DIM + ln * 4);
    float s = v.x * v.x + v.y * v.y + v.z * v.z + v.w * v.w;
#pragma unroll
    for (int off = 32; off > 0; off >>= 1) s += __shfl_xor(s, off);
    if (ln == 0) enorm[k] = s;
}

// ---------------- kernel 1: argmin GEMM ----------------
// block: 256 threads (tx=tid&15 -> col group, ty=tid>>4 -> row group)
// per-thread micro-tile: 4 rows x 8 cols (cols tx*4..+3 and 64+tx*4..+3 of chunk)
__global__ __launch_bounds__(256, 2)
void argmin_kernel(const float* __restrict__ z, const float* __restrict__ emb,
                   const float* __restrict__ enorm_g, float* __restrict__ idx_out) {
    __shared__ float z_t[DIM][TILE_M];     // [d][row], row swizzled: row ^ (d & 28)
    __shared__ float e_t[DSLICE][KCHUNK];  // [d][k],   k   swizzled: k   ^ ((d & 7) << 2)

    const int tid = threadIdx.x;
    const int tx = tid & 15;
    const int ty = tid >> 4;
    const int wv = tid >> 6;
    const int ln = tid & 63;

    const float* zblk = z + (size_t)blockIdx.x * (TILE_M * DIM);

    // ---- stage z tile (transposed + swizzled) and compute per-row |z|^2 ----
    float* znbuf = &e_t[0][0];  // scratch: 64 floats, consumed before first e-slice store
#pragma unroll
    for (int it = 0; it < 16; ++it) {
        const int idx = tid * 4 + it * 1024;
        const int row = idx >> 8;
        const int d0  = idx & 255;
        const float4 v = *reinterpret_cast<const float4*>(zblk + idx);
        const int rs = row ^ (d0 & 28);   // (d0+j)&28 == d0&28 for j<4
        z_t[d0 + 0][rs] = v.x;
        z_t[d0 + 1][rs] = v.y;
        z_t[d0 + 2][rs] = v.z;
        z_t[d0 + 3][rs] = v.w;
        float p = v.x * v.x + v.y * v.y + v.z * v.z + v.w * v.w;
#pragma unroll
        for (int off = 32; off > 0; off >>= 1) p += __shfl_xor(p, off);
        if (ln == 0) znbuf[wv + 4 * it] = p;  // all lanes of wave wv hold row wv+4*it this it
    }
    __syncthreads();
    float zn4[4];
#pragma unroll
    for (int m = 0; m < 4; ++m) zn4[m] = znbuf[ty * 4 + m];
    __syncthreads();   // scratch reads done before e_t is overwritten

    // ---- prefetch + store slice 0 (kc=0, dc=0) ----
    float4 pf[4];
    {
        const int k0 = tid >> 3;
        const int d0 = (tid & 7) << 2;
#pragma unroll
        for (int it = 0; it < 4; ++it)
            pf[it] = *reinterpret_cast<const float4*>(emb + (k0 + it * 32) * DIM + d0);
#pragma unroll
        for (int it = 0; it < 4; ++it) {
            const int k = k0 + it * 32;
#pragma unroll
            for (int j = 0; j < 4; ++j) {
                const int d = d0 + j;
                e_t[d][k ^ ((d & 7) << 2)] = reinterpret_cast<const float*>(&pf[it])[j];
            }
        }
    }

    float acc[4][8];
#pragma unroll
    for (int m = 0; m < 4; ++m)
#pragma unroll
        for (int c = 0; c < 8; ++c) acc[m][c] = 0.f;
    float best[4];
    int   bidx[4];
#pragma unroll
    for (int m = 0; m < 4; ++m) { best[m] = 3.4e38f; bidx[m] = 0; }

#pragma unroll 1
    for (int kc = 0; kc < NCODE / KCHUNK; ++kc) {
#pragma unroll 1
        for (int dc = 0; dc < DIM / DSLICE; ++dc) {
            __syncthreads();   // current slice visible in e_t
            const int s1 = kc * 8 + dc + 1;
            if (s1 < 64) {     // issue next-slice global loads (hidden under compute)
                const float* base = emb + (s1 >> 3) * (KCHUNK * DIM) + (s1 & 7) * DSLICE;
                const int k0 = tid >> 3;
                const int d0 = (tid & 7) << 2;
#pragma unroll
                for (int it = 0; it < 4; ++it)
                    pf[it] = *reinterpret_cast<const float4*>(base + (k0 + it * 32) * DIM + d0);
            }
#pragma unroll
            for (int dd = 0; dd < DSLICE; ++dd) {
                const int dg = dc * DSLICE + dd;
                const float4 a  = *reinterpret_cast<const float4*>(&z_t[dg][(ty << 2) ^ (dd & 28)]);
                const int bs = (dd & 7) << 2;
                const float4 b0 = *reinterpret_cast<const float4*>(&e_t[dd][(tx << 2) ^ bs]);
                const float4 b1 = *reinterpret_cast<const float4*>(&e_t[dd][64 + ((tx << 2) ^ bs)]);
                const float av[4] = {a.x, a.y, a.z, a.w};
                const float bv[8] = {b0.x, b0.y, b0.z, b0.w, b1.x, b1.y, b1.z, b1.w};
#pragma unroll
                for (int m = 0; m < 4; ++m)
#pragma unroll
                    for (int c = 0; c < 8; ++c)
                        acc[m][c] = fmaf(av[m], bv[c], acc[m][c]);
            }
            __syncthreads();   // all reads of e_t done
            if (s1 < 64) {     // write next slice
                const int k0 = tid >> 3;
                const int d0 = (tid & 7) << 2;
#pragma unroll
                for (int it = 0; it < 4; ++it) {
                    const int k = k0 + it * 32;
#pragma unroll
                    for (int j = 0; j < 4; ++j) {
                        const int d = d0 + j;
                        e_t[d][k ^ ((d & 7) << 2)] = reinterpret_cast<const float*>(&pf[it])[j];
                    }
                }
            }
        }
        // ---- epilogue for this k-chunk: dist = (|z|^2 + |e|^2) - 2*dot ----
#pragma unroll
        for (int c = 0; c < 8; ++c) {
            const int col = kc * KCHUNK + ((c < 4) ? ((tx << 2) + c) : (64 + (tx << 2) + (c - 4)));
            const float en = enorm_g[col];
#pragma unroll
            for (int m = 0; m < 4; ++m) {
                const float v = fmaf(-2.f, acc[m][c], zn4[m] + en);
                if (v < best[m]) { best[m] = v; bidx[m] = col; }  // strict < : first-min tie-break
                acc[m][c] = 0.f;
            }
        }
    }

    // ---- reduce (min,idx) across the 16 tx lanes sharing each row group ----
#pragma unroll
    for (int off = 1; off < 16; off <<= 1) {
#pragma unroll
        for (int m = 0; m < 4; ++m) {
            const float ov = __shfl_xor(best[m], off);
            const int   oi = __shfl_xor(bidx[m], off);
            if (ov < best[m] || (ov == best[m] && oi < bidx[m])) { best[m] = ov; bidx[m] = oi; }
        }
    }
    if (tx == 0) {
#pragma unroll
        for (int m = 0; m < 4; ++m)
            idx_out[(size_t)blockIdx.x * TILE_M + ty * 4 + m] = (float)bidx[m];
    }
}

// ---------------- kernel 2: gather + quantized output + per-block loss partial ----------------
__global__ __launch_bounds__(256)
void gather_kernel(const float* __restrict__ z, const float* __restrict__ emb,
                   const float* __restrict__ idx_f, float* __restrict__ q_out,
                   float* __restrict__ partials) {
    const int wv = threadIdx.x >> 6, ln = threadIdx.x & 63;
    float lsum = 0.f;
#pragma unroll
    for (int i = 0; i < 16; ++i) {
        const size_t row = (size_t)blockIdx.x * 64 + i * 4 + wv;
        const int kidx = (int)idx_f[row];
        const float4 e4 = *reinterpret_cast<const float4*>(emb + (size_t)kidx * DIM + ln * 4);
        const float4 z4 = *reinterpret_cast<const float4*>(z + row * DIM + ln * 4);
        *reinterpret_cast<float4*>(q_out + row * DIM + ln * 4) = e4;  // quantized_st == quantized
        const float dx = e4.x - z4.x, dy = e4.y - z4.y, dz = e4.z - z4.z, dw = e4.w - z4.w;
        lsum += dx * dx + dy * dy + dz * dz + dw * dw;
    }
#pragma unroll
    for (int off = 32; off > 0; off >>= 1) lsum += __shfl_xor(lsum, off);
    __shared__ float red[4];
    if (ln == 0) red[wv] = lsum;
    __syncthreads();
    if (threadIdx.x == 0) partials[blockIdx.x] = red[0] + red[1] + red[2] + red[3];
}

// ---------------- kernel 3: deterministic loss reduction ----------------
__global__ __launch_bounds__(256)
void loss_kernel(const float* __restrict__ partials, float* __restrict__ loss_out) {
    const int tid = threadIdx.x;
    float s = partials[tid] + partials[tid + 256] + partials[tid + 512] + partials[tid + 768];
#pragma unroll
    for (int off = 32; off > 0; off >>= 1) s += __shfl_xor(s, off);
    __shared__ float red[4];
    if ((tid & 63) == 0) red[tid >> 6] = s;
    __syncthreads();
    if (tid == 0)
        loss_out[0] = (red[0] + red[1] + red[2] + red[3]) * (1.25f / 16777216.0f);
}

extern "C" void kernel_launch(void* const* d_in, const int* in_sizes, int n_in,
                              void* d_out, int out_size, void* d_ws, size_t ws_size,
                              hipStream_t stream) {
    const float* z   = (const float*)d_in[0];
    const float* emb = (const float*)d_in[1];
    float* out      = (float*)d_out;
    float* q_out    = out;                       // 16,777,216 floats
    float* loss_out = out + 16777216;            // 1 float
    float* idx_out  = out + 16777217;            // 65,536 floats (indices as float)
    float* enorm    = (float*)d_ws;              // 1024 floats
    float* partials = (float*)d_ws + 1024;       // 1024 floats

    enorm_kernel<<<NCODE / 4, 256, 0, stream>>>(emb, enorm);
    argmin_kernel<<<N_ROWS / TILE_M, 256, 0, stream>>>(z, emb, enorm, idx_out);
    gather_kernel<<<N_ROWS / 64, 256, 0, stream>>>(z, emb, idx_out, q_out, partials);
    loss_kernel<<<1, 256, 0, stream>>>(partials, loss_out);
}

// Round 2
// 4330.484 us; speedup vs baseline: 1.0274x; 1.0274x over previous
//
#include <hip/hip_runtime.h>

// Problem: VectorQuantizer — z:(16,256,64,64) f32, emb:(1024,256) f32 (row-normalized)
// flat_z rows are CONTIGUOUS 256-float chunks of z (torch .view semantics).
// N=65536 rows, D=256, K=1024.
// d_out layout (float32): q[16777216] | vq_loss[1] | indices_as_float[65536]
//
// R1 lesson: address-taken local arrays (pf[4] via reinterpret_cast, av/bv)
// defeated SROA -> 21 GB of scratch HBM traffic, 4.6 ms. This version has NO
// local arrays in the hot path: named float4 registers only.

#define N_ROWS   65536
#define DIM      256
#define NCODE    1024
#define TILE_M   64          // rows per block
#define KCHUNK   128         // codes per k-chunk
#define DSLICE   32          // d per staged e-slice

// ---------------- kernel 0: embedding row norms ----------------
__global__ __launch_bounds__(256)
void enorm_kernel(const float* __restrict__ emb, float* __restrict__ enorm) {
    const int wv = threadIdx.x >> 6, ln = threadIdx.x & 63;
    const int k = blockIdx.x * 4 + wv;
    const float4 v = *reinterpret_cast<const float4*>(emb + (size_t)k * DIM + ln * 4);
    float s = v.x * v.x + v.y * v.y + v.z * v.z + v.w * v.w;
#pragma unroll
    for (int off = 32; off > 0; off >>= 1) s += __shfl_xor(s, off);
    if (ln == 0) enorm[k] = s;
}

// ---------------- kernel 1: argmin GEMM ----------------
// block: 256 threads (tx=tid&15 -> col group, ty=tid>>4 -> row group)
// per-thread micro-tile: 4 rows x 8 cols (cols tx*4..+3 and 64+tx*4..+3 of chunk)

#define PF_LOAD(BASE) \
    pf0 = *reinterpret_cast<const float4*>((BASE) + (k0 +  0) * DIM + d0); \
    pf1 = *reinterpret_cast<const float4*>((BASE) + (k0 + 32) * DIM + d0); \
    pf2 = *reinterpret_cast<const float4*>((BASE) + (k0 + 64) * DIM + d0); \
    pf3 = *reinterpret_cast<const float4*>((BASE) + (k0 + 96) * DIM + d0);

#define PF_STORE(PF, IT) { \
    const int k_ = k0 + (IT) * 32; \
    e_t[d0 + 0][k_ ^ (((d0 + 0) & 7) << 2)] = PF.x; \
    e_t[d0 + 1][k_ ^ (((d0 + 1) & 7) << 2)] = PF.y; \
    e_t[d0 + 2][k_ ^ (((d0 + 2) & 7) << 2)] = PF.z; \
    e_t[d0 + 3][k_ ^ (((d0 + 3) & 7) << 2)] = PF.w; }

#define FMA8(AM, LO, HI) \
    LO.x = fmaf(AM, b0.x, LO.x); LO.y = fmaf(AM, b0.y, LO.y); \
    LO.z = fmaf(AM, b0.z, LO.z); LO.w = fmaf(AM, b0.w, LO.w); \
    HI.x = fmaf(AM, b1.x, HI.x); HI.y = fmaf(AM, b1.y, HI.y); \
    HI.z = fmaf(AM, b1.z, HI.z); HI.w = fmaf(AM, b1.w, HI.w);

#define UPD1(V, EN, COL, BEST, BIDX, ZN) { \
    const float d_ = fmaf(-2.f, V, ZN + EN); \
    if (d_ < BEST) { BEST = d_; BIDX = COL; } }

#define UPDROW(LO, HI, BEST, BIDX, ZN) \
    UPD1(LO.x, enA0, c0 + 0,  BEST, BIDX, ZN) \
    UPD1(LO.y, enA1, c0 + 1,  BEST, BIDX, ZN) \
    UPD1(LO.z, enA2, c0 + 2,  BEST, BIDX, ZN) \
    UPD1(LO.w, enA3, c0 + 3,  BEST, BIDX, ZN) \
    UPD1(HI.x, enB0, c0 + 64, BEST, BIDX, ZN) \
    UPD1(HI.y, enB1, c0 + 65, BEST, BIDX, ZN) \
    UPD1(HI.z, enB2, c0 + 66, BEST, BIDX, ZN) \
    UPD1(HI.w, enB3, c0 + 67, BEST, BIDX, ZN)

#define RED1(B, I) { \
    const float ov_ = __shfl_xor(B, off); \
    const int   oi_ = __shfl_xor(I, off); \
    if (ov_ < B || (ov_ == B && oi_ < I)) { B = ov_; I = oi_; } }

__global__ __launch_bounds__(256, 2)
void argmin_kernel(const float* __restrict__ z, const float* __restrict__ emb,
                   const float* __restrict__ enorm_g, float* __restrict__ idx_out) {
    __shared__ float z_t[DIM][TILE_M];     // [d][row], row swizzled: row ^ (d & 28)
    __shared__ float e_t[DSLICE][KCHUNK];  // [d][k],   k   swizzled: k   ^ ((d & 7) << 2)

    const int tid = threadIdx.x;
    const int tx = tid & 15;
    const int ty = tid >> 4;
    const int wv = tid >> 6;
    const int ln = tid & 63;
    const int k0 = tid >> 3;         // e-slice staging: code row
    const int d0 = (tid & 7) << 2;   // e-slice staging: d offset within slice

    const float* zblk = z + (size_t)blockIdx.x * (TILE_M * DIM);

    // ---- stage z tile (transposed + swizzled) and compute per-row |z|^2 ----
    float* znbuf = &e_t[0][0];  // LDS scratch: 64 floats, consumed before first e-slice store
#pragma unroll
    for (int it = 0; it < 16; ++it) {
        const int idx = tid * 4 + it * 1024;
        const int row = idx >> 8;
        const int dz0 = idx & 255;
        const float4 v = *reinterpret_cast<const float4*>(zblk + idx);
        const int rs = row ^ (dz0 & 28);   // (dz0+j)&28 == dz0&28 for j<4
        z_t[dz0 + 0][rs] = v.x;
        z_t[dz0 + 1][rs] = v.y;
        z_t[dz0 + 2][rs] = v.z;
        z_t[dz0 + 3][rs] = v.w;
        float p = v.x * v.x + v.y * v.y + v.z * v.z + v.w * v.w;
#pragma unroll
        for (int off = 32; off > 0; off >>= 1) p += __shfl_xor(p, off);
        if (ln == 0) znbuf[wv + 4 * it] = p;  // all lanes of wave wv hold row wv+4*it this it
    }
    __syncthreads();
    float zn0 = znbuf[ty * 4 + 0];
    float zn1 = znbuf[ty * 4 + 1];
    float zn2 = znbuf[ty * 4 + 2];
    float zn3 = znbuf[ty * 4 + 3];
    __syncthreads();   // scratch reads done before e_t is overwritten

    // ---- prefetch + store slice 0 (kc=0, dc=0) ----
    float4 pf0, pf1, pf2, pf3;
    PF_LOAD(emb)
    PF_STORE(pf0, 0) PF_STORE(pf1, 1) PF_STORE(pf2, 2) PF_STORE(pf3, 3)

    float4 acc0a = {0,0,0,0}, acc0b = {0,0,0,0};
    float4 acc1a = {0,0,0,0}, acc1b = {0,0,0,0};
    float4 acc2a = {0,0,0,0}, acc2b = {0,0,0,0};
    float4 acc3a = {0,0,0,0}, acc3b = {0,0,0,0};
    float best0 = 3.4e38f, best1 = 3.4e38f, best2 = 3.4e38f, best3 = 3.4e38f;
    int   bidx0 = 0, bidx1 = 0, bidx2 = 0, bidx3 = 0;

#pragma unroll 1
    for (int kc = 0; kc < NCODE / KCHUNK; ++kc) {
#pragma unroll 1
        for (int dc = 0; dc < DIM / DSLICE; ++dc) {
            __syncthreads();   // current slice visible in e_t
            const int s1 = kc * 8 + dc + 1;
            if (s1 < 64) {     // issue next-slice global loads (hidden under compute)
                const float* base = emb + (s1 >> 3) * (KCHUNK * DIM) + (s1 & 7) * DSLICE;
                PF_LOAD(base)
            }
#pragma unroll
            for (int dd = 0; dd < DSLICE; ++dd) {
                const int dg = dc * DSLICE + dd;
                const float4 a  = *reinterpret_cast<const float4*>(&z_t[dg][(ty << 2) ^ (dd & 28)]);
                const int bs = (dd & 7) << 2;
                const float4 b0 = *reinterpret_cast<const float4*>(&e_t[dd][(tx << 2) ^ bs]);
                const float4 b1 = *reinterpret_cast<const float4*>(&e_t[dd][64 + ((tx << 2) ^ bs)]);
                FMA8(a.x, acc0a, acc0b)
                FMA8(a.y, acc1a, acc1b)
                FMA8(a.z, acc2a, acc2b)
                FMA8(a.w, acc3a, acc3b)
            }
            __syncthreads();   // all reads of e_t done
            if (s1 < 64) {     // write next slice
                PF_STORE(pf0, 0) PF_STORE(pf1, 1) PF_STORE(pf2, 2) PF_STORE(pf3, 3)
            }
        }
        // ---- epilogue for this k-chunk: dist = (|z|^2 + |e|^2) - 2*dot ----
        const int c0 = kc * KCHUNK + (tx << 2);
        const float enA0 = enorm_g[c0 + 0],  enA1 = enorm_g[c0 + 1];
        const float enA2 = enorm_g[c0 + 2],  enA3 = enorm_g[c0 + 3];
        const float enB0 = enorm_g[c0 + 64], enB1 = enorm_g[c0 + 65];
        const float enB2 = enorm_g[c0 + 66], enB3 = enorm_g[c0 + 67];
        UPDROW(acc0a, acc0b, best0, bidx0, zn0)
        UPDROW(acc1a, acc1b, best1, bidx1, zn1)
        UPDROW(acc2a, acc2b, best2, bidx2, zn2)
        UPDROW(acc3a, acc3b, best3, bidx3, zn3)
        acc0a = {0,0,0,0}; acc0b = {0,0,0,0};
        acc1a = {0,0,0,0}; acc1b = {0,0,0,0};
        acc2a = {0,0,0,0}; acc2b = {0,0,0,0};
        acc3a = {0,0,0,0}; acc3b = {0,0,0,0};
    }

    // ---- reduce (min,idx) across the 16 tx lanes sharing each row group ----
#pragma unroll
    for (int off = 1; off < 16; off <<= 1) {
        RED1(best0, bidx0)
        RED1(best1, bidx1)
        RED1(best2, bidx2)
        RED1(best3, bidx3)
    }
    if (tx == 0) {
        float* o = idx_out + (size_t)blockIdx.x * TILE_M + ty * 4;
        o[0] = (float)bidx0;
        o[1] = (float)bidx1;
        o[2] = (float)bidx2;
        o[3] = (float)bidx3;
    }
}

// ---------------- kernel 2: gather + quantized output + per-block loss partial ----------------
__global__ __launch_bounds__(256)
void gather_kernel(const float* __restrict__ z, const float* __restrict__ emb,
                   const float* __restrict__ idx_f, float* __restrict__ q_out,
                   float* __restrict__ partials) {
    const int wv = threadIdx.x >> 6, ln = threadIdx.x & 63;
    float lsum = 0.f;
#pragma unroll
    for (int i = 0; i < 16; ++i) {
        const size_t row = (size_t)blockIdx.x * 64 + i * 4 + wv;
        const int kidx = (int)idx_f[row];
        const float4 e4 = *reinterpret_cast<const float4*>(emb + (size_t)kidx * DIM + ln * 4);
        const float4 z4 = *reinterpret_cast<const float4*>(z + row * DIM + ln * 4);
        *reinterpret_cast<float4*>(q_out + row * DIM + ln * 4) = e4;  // quantized_st == quantized
        const float dx = e4.x - z4.x, dy = e4.y - z4.y, dz = e4.z - z4.z, dw = e4.w - z4.w;
        lsum += dx * dx + dy * dy + dz * dz + dw * dw;
    }
#pragma unroll
    for (int off = 32; off > 0; off >>= 1) lsum += __shfl_xor(lsum, off);
    __shared__ float red[4];
    if (ln == 0) red[wv] = lsum;
    __syncthreads();
    if (threadIdx.x == 0) partials[blockIdx.x] = red[0] + red[1] + red[2] + red[3];
}

// ---------------- kernel 3: deterministic loss reduction ----------------
__global__ __launch_bounds__(256)
void loss_kernel(const float* __restrict__ partials, float* __restrict__ loss_out) {
    const int tid = threadIdx.x;
    float s = partials[tid] + partials[tid + 256] + partials[tid + 512] + partials[tid + 768];
#pragma unroll
    for (int off = 32; off > 0; off >>= 1) s += __shfl_xor(s, off);
    __shared__ float red[4];
    if ((tid & 63) == 0) red[tid >> 6] = s;
    __syncthreads();
    if (tid == 0)
        loss_out[0] = (red[0] + red[1] + red[2] + red[3]) * (1.25f / 16777216.0f);
}

extern "C" void kernel_launch(void* const* d_in, const int* in_sizes, int n_in,
                              void* d_out, int out_size, void* d_ws, size_t ws_size,
                              hipStream_t stream) {
    const float* z   = (const float*)d_in[0];
    const float* emb = (const float*)d_in[1];
    float* out      = (float*)d_out;
    float* q_out    = out;                       // 16,777,216 floats
    float* loss_out = out + 16777216;            // 1 float
    float* idx_out  = out + 16777217;            // 65,536 floats (indices as float)
    float* enorm    = (float*)d_ws;              // 1024 floats
    float* partials = (float*)d_ws + 1024;       // 1024 floats

    enorm_kernel<<<NCODE / 4, 256, 0, stream>>>(emb, enorm);
    argmin_kernel<<<N_ROWS / TILE_M, 256, 0, stream>>>(z, emb, enorm, idx_out);
    gather_kernel<<<N_ROWS / 64, 256, 0, stream>>>(z, emb, idx_out, q_out, partials);
    loss_kernel<<<1, 256, 0, stream>>>(partials, loss_out);
}

// Round 3
// 829.919 us; speedup vs baseline: 5.3608x; 5.2180x over previous
//
#include <hip/hip_runtime.h>
#include <stdint.h>

// VectorQuantizer — z:(16,256,64,64) f32 -> rows of 256; emb:(1024,256) f32.
// N=65536, D=256, K=1024. d_out: q[16777216] | vq_loss[1] | idx_as_float[65536]
//
// R3: ALL staging via global_load_lds (no register staging — R1/R2 showed 21 GB
// of phantom HBM traffic with the global->reg->LDS path regardless of codegen).
// Linear LDS dest + pre-swizzled global source + swizzled LDS reads (m173/m201).
// Double-buffered 8KB e-slices, counted vmcnt(2), 2 barriers/slice, 2 blocks/CU.

#define DOT4(ACC, A, B) \
    ACC = fmaf(A.x, B.x, ACC); ACC = fmaf(A.y, B.y, ACC); \
    ACC = fmaf(A.z, B.z, ACC); ACC = fmaf(A.w, B.w, ACC);

#define WAITVM(N) asm volatile("s_waitcnt vmcnt(" #N ")" ::: "memory")

__device__ __forceinline__ void gload16(const float* gp, float* lp) {
    __builtin_amdgcn_global_load_lds(
        (const __attribute__((address_space(1))) void*)gp,
        (__attribute__((address_space(3))) void*)lp, 16, 0, 0);
}

// ---------------- kernel 0: embedding row norms ----------------
__global__ __launch_bounds__(256)
void enorm_kernel(const float* __restrict__ emb, float* __restrict__ enorm) {
    const int wv = threadIdx.x >> 6, ln = threadIdx.x & 63;
    const int k = blockIdx.x * 4 + wv;
    const float4 v = *reinterpret_cast<const float4*>(emb + (size_t)k * 256 + ln * 4);
    float s = v.x * v.x + v.y * v.y + v.z * v.z + v.w * v.w;
#pragma unroll
    for (int off = 32; off > 0; off >>= 1) s += __shfl_xor(s, off);
    if (ln == 0) enorm[k] = s;
}

// ---------------- kernel 1: argmin GEMM (DMA-staged) ----------------
// 256 thr; tx=tid&15 -> codes tx+16c (c=0..7); ty=tid>>4 -> rows ty+16m (m=0..3)

#define ISSUE_SLICE(S, B) { \
    const int kc_ = (S) >> 4; \
    const int db_ = ((S) & 15) << 4; \
    const int kkB = kk_base + 64; \
    gload16(emb + ((kc_ << 7) + kk_base) * 256 + db_ + (ep0 ^ ((kk_base & 3) << 2)), \
            &e_lds[B][(kk_base << 4) + ep0]); \
    gload16(emb + ((kc_ << 7) + kkB) * 256 + db_ + (ep0 ^ ((kkB & 3) << 2)), \
            &e_lds[B][(kkB << 4) + ep0]); }

#define EB(C) { \
    const int kk = tx + (C << 4); \
    const float4 b_ = *reinterpret_cast<const float4*>( \
        &e_lds[b][(kk << 4) + (dq ^ ((kk & 3) << 2))]); \
    DOT4(acc##C.x, a0, b_) DOT4(acc##C.y, a1, b_) \
    DOT4(acc##C.z, a2, b_) DOT4(acc##C.w, a3, b_) }

#define UPDC(C) { \
    const int col = (kc << 7) + (C << 4) + tx; \
    const float en = enorm_g[col]; \
    float d_; \
    d_ = fmaf(-2.f, acc##C.x, zn0 + en); if (d_ < best0) { best0 = d_; bidx0 = col; } \
    d_ = fmaf(-2.f, acc##C.y, zn1 + en); if (d_ < best1) { best1 = d_; bidx1 = col; } \
    d_ = fmaf(-2.f, acc##C.z, zn2 + en); if (d_ < best2) { best2 = d_; bidx2 = col; } \
    d_ = fmaf(-2.f, acc##C.w, zn3 + en); if (d_ < best3) { best3 = d_; bidx3 = col; } \
    acc##C = make_float4(0.f, 0.f, 0.f, 0.f); }

#define RED1(B, I) { \
    const float ov_ = __shfl_xor(B, off); \
    const int   oi_ = __shfl_xor(I, off); \
    if (ov_ < B || (ov_ == B && oi_ < I)) { B = ov_; I = oi_; } }

__global__ __launch_bounds__(256, 2)
void argmin_kernel(const float* __restrict__ z, const float* __restrict__ emb,
                   const float* __restrict__ enorm_g, float* __restrict__ idx_out) {
    __shared__ float z_lds[16384];     // [row][d'] , d' = d ^ ((row&7)<<2)   (64 KB)
    __shared__ float e_lds[2][2048];   // [k][d']   , d' = d ^ ((k&3)<<2)     (2 x 8 KB)

    const int tid = threadIdx.x;
    const int wv = tid >> 6, ln = tid & 63;
    const int tx = tid & 15, ty = tid >> 4;
    const int kk_base = (wv << 4) + (ln >> 2);   // e-staging code row
    const int ep0 = (ln & 3) << 2;               // e-staging d' offset

    const float* zblk = z + (size_t)blockIdx.x * (64 * 256);

    // ---- stage z tile via DMA: call c -> wave wv loads row 4c+wv ----
    {
        const int dp0 = ln << 2;
#pragma unroll
        for (int c = 0; c < 16; ++c) {
            const int r = (c << 2) + wv;
            const int swz = (r & 7) << 2;
            gload16(zblk + r * 256 + (dp0 ^ swz), &z_lds[(r << 8) + dp0]);
        }
    }
    WAITVM(0);
    __syncthreads();

    // overlap slice-0 e-DMA (into buf0) with the zn pass (scratch = buf1)
    ISSUE_SLICE(0, 0)

    // ---- per-row |z|^2 from LDS: thread handles row wv*16+(ln>>2), quarter ln&3 ----
    float* znscr = &e_lds[1][0];
    {
        const int r = (wv << 4) + (ln >> 2);
        const int q4 = ln & 3;
        const int swz = (r & 7) << 2;
        float s0 = 0.f;
#pragma unroll
        for (int j = 0; j < 16; ++j) {
            const int d = (q4 << 6) + (j << 2);
            const float4 v = *reinterpret_cast<const float4*>(&z_lds[(r << 8) + (d ^ swz)]);
            s0 = fmaf(v.x, v.x, fmaf(v.y, v.y, fmaf(v.z, v.z, fmaf(v.w, v.w, s0))));
        }
        s0 += __shfl_xor(s0, 1);
        s0 += __shfl_xor(s0, 2);
        if (q4 == 0) znscr[r] = s0;
    }
    __syncthreads();
    const float zn0 = znscr[ty];
    const float zn1 = znscr[ty + 16];
    const float zn2 = znscr[ty + 32];
    const float zn3 = znscr[ty + 48];
    __syncthreads();   // zn consumed before slice-1 DMA may touch buf1

    float4 acc0 = {0,0,0,0}, acc1 = {0,0,0,0}, acc2 = {0,0,0,0}, acc3 = {0,0,0,0};
    float4 acc4 = {0,0,0,0}, acc5 = {0,0,0,0}, acc6 = {0,0,0,0}, acc7 = {0,0,0,0};
    float best0 = 3.4e38f, best1 = 3.4e38f, best2 = 3.4e38f, best3 = 3.4e38f;
    int   bidx0 = 0, bidx1 = 0, bidx2 = 0, bidx3 = 0;

    const int zsw = (ty & 7) << 2;

#pragma unroll 1
    for (int kc = 0; kc < 8; ++kc) {
#pragma unroll 1
        for (int dc = 0; dc < 16; ++dc) {
            const int s = (kc << 4) + dc;
            const int b = s & 1;
            if (s < 127) {
                ISSUE_SLICE(s + 1, (s + 1) & 1)
                WAITVM(2);            // drain slice-s loads; keep s+1's 2 in flight
            } else {
                WAITVM(0);
            }
            __syncthreads();          // slice s visible in e_lds[b] (all waves waited)
#pragma unroll
            for (int q = 0; q < 4; ++q) {
                const int zoff = (((dc << 4) + (q << 2)) ^ zsw);
                const float4 a0 = *reinterpret_cast<const float4*>(&z_lds[((ty      ) << 8) + zoff]);
                const float4 a1 = *reinterpret_cast<const float4*>(&z_lds[((ty + 16) << 8) + zoff]);
                const float4 a2 = *reinterpret_cast<const float4*>(&z_lds[((ty + 32) << 8) + zoff]);
                const float4 a3 = *reinterpret_cast<const float4*>(&z_lds[((ty + 48) << 8) + zoff]);
                const int dq = q << 2;
                EB(0) EB(1) EB(2) EB(3)
                EB(4) EB(5) EB(6) EB(7)
            }
            __syncthreads();          // reads of e_lds[b] done before it is re-DMAed
        }
        UPDC(0) UPDC(1) UPDC(2) UPDC(3) UPDC(4) UPDC(5) UPDC(6) UPDC(7)
    }

    // ---- (min,idx) reduce across the 16 tx lanes sharing each row ----
#pragma unroll
    for (int off = 1; off < 16; off <<= 1) {
        RED1(best0, bidx0)
        RED1(best1, bidx1)
        RED1(best2, bidx2)
        RED1(best3, bidx3)
    }
    if (tx == 0) {
        float* o = idx_out + (size_t)blockIdx.x * 64 + ty;
        o[0]  = (float)bidx0;
        o[16] = (float)bidx1;
        o[32] = (float)bidx2;
        o[48] = (float)bidx3;
    }
}

// ---------------- kernel 2: gather + quantized output + loss partials ----------------
__global__ __launch_bounds__(256)
void gather_kernel(const float* __restrict__ z, const float* __restrict__ emb,
                   const float* __restrict__ idx_f, float* __restrict__ q_out,
                   float* __restrict__ partials) {
    const int wv = threadIdx.x >> 6, ln = threadIdx.x & 63;
    float lsum = 0.f;
#pragma unroll
    for (int i = 0; i < 16; ++i) {
        const size_t row = (size_t)blockIdx.x * 64 + i * 4 + wv;
        const int kidx = (int)idx_f[row];
        const float4 e4 = *reinterpret_cast<const float4*>(emb + (size_t)kidx * 256 + ln * 4);
        const float4 z4 = *reinterpret_cast<const float4*>(z + row * 256 + ln * 4);
        *reinterpret_cast<float4*>(q_out + row * 256 + ln * 4) = e4;  // quantized_st == quantized
        const float dx = e4.x - z4.x, dy = e4.y - z4.y, dz = e4.z - z4.z, dw = e4.w - z4.w;
        lsum += dx * dx + dy * dy + dz * dz + dw * dw;
    }
#pragma unroll
    for (int off = 32; off > 0; off >>= 1) lsum += __shfl_xor(lsum, off);
    __shared__ float red[4];
    if (ln == 0) red[wv] = lsum;
    __syncthreads();
    if (threadIdx.x == 0) partials[blockIdx.x] = red[0] + red[1] + red[2] + red[3];
}

// ---------------- kernel 3: deterministic loss reduction ----------------
__global__ __launch_bounds__(256)
void loss_kernel(const float* __restrict__ partials, float* __restrict__ loss_out) {
    const int tid = threadIdx.x;
    float s = partials[tid] + partials[tid + 256] + partials[tid + 512] + partials[tid + 768];
#pragma unroll
    for (int off = 32; off > 0; off >>= 1) s += __shfl_xor(s, off);
    __shared__ float red[4];
    if ((tid & 63) == 0) red[tid >> 6] = s;
    __syncthreads();
    if (tid == 0)
        loss_out[0] = (red[0] + red[1] + red[2] + red[3]) * (1.25f / 16777216.0f);
}

extern "C" void kernel_launch(void* const* d_in, const int* in_sizes, int n_in,
                              void* d_out, int out_size, void* d_ws, size_t ws_size,
                              hipStream_t stream) {
    const float* z   = (const float*)d_in[0];
    const float* emb = (const float*)d_in[1];
    float* out      = (float*)d_out;
    float* q_out    = out;                       // 16,777,216 floats
    float* loss_out = out + 16777216;            // 1 float
    float* idx_out  = out + 16777217;            // 65,536 floats
    float* enorm    = (float*)d_ws;              // 1024 floats
    float* partials = (float*)d_ws + 1024;       // 1024 floats

    enorm_kernel<<<256, 256, 0, stream>>>(emb, enorm);
    argmin_kernel<<<1024, 256, 0, stream>>>(z, emb, enorm, idx_out);
    gather_kernel<<<1024, 256, 0, stream>>>(z, emb, idx_out, q_out, partials);
    loss_kernel<<<1, 256, 0, stream>>>(partials, loss_out);
}